// Round 2
// baseline (2385.428 us; speedup 1.0000x reference)
//
#include <hip/hip_runtime.h>
#include <math.h>

// Problem constants: B=16, T=64, V=50257, E=512, H=1024, L=2
#define Bc 16
#define Tc 64
#define Vc 50257
#define Ec 512
#define Hc 1024
#define SCAN_BLOCKS 256

typedef __attribute__((ext_vector_type(4))) float f32x4;
typedef __attribute__((ext_vector_type(8))) __bf16 bf16x8;

__device__ __forceinline__ float dot4(float4 a, float4 b) {
    return a.x * b.x + a.y * b.y + a.z * b.z + a.w * b.w;
}
__device__ __forceinline__ float sigm(float x) { return 1.0f / (1.0f + expf(-x)); }

// round-to-nearest-even float -> bf16 bits (finite inputs)
__device__ __forceinline__ unsigned short f2b(float f) {
    unsigned u = __float_as_uint(f);
    unsigned r = u + 0x7fffu + ((u >> 16) & 1u);
    return (unsigned short)(r >> 16);
}
__device__ __forceinline__ float b2f(unsigned short b) {
    return __uint_as_float(((unsigned)b) << 16);
}
__device__ __forceinline__ float2 u2f2(unsigned long long u) {
    union { unsigned long long u; float2 f; } c;
    c.u = u;
    return c.f;
}
__device__ __forceinline__ unsigned long long f22u(float a, float b) {
    union { float f[2]; unsigned long long u; } c;
    c.f[0] = a;
    c.f[1] = b;
    return c.u;
}

// ---------------------------------------------------------------------------
// split fp32 -> (hi, lo) bf16 pair, 4 elements/thread
// ---------------------------------------------------------------------------
__global__ __launch_bounds__(256) void split_bf16_4(const float4* __restrict__ x,
                                                    ushort4* __restrict__ hi,
                                                    ushort4* __restrict__ lo, int n4) {
    int i = blockIdx.x * 256 + threadIdx.x;
    for (; i < n4; i += gridDim.x * 256) {
        float4 v = x[i];
        ushort4 h, l;
        h.x = f2b(v.x); l.x = f2b(v.x - b2f(h.x));
        h.y = f2b(v.y); l.y = f2b(v.y - b2f(h.y));
        h.z = f2b(v.z); l.z = f2b(v.z - b2f(h.z));
        h.w = f2b(v.w); l.w = f2b(v.w - b2f(h.w));
        hi[i] = h;
        lo[i] = l;
    }
}

// ---------------------------------------------------------------------------
// Build X0 (T*B, 2E): row m=t*B+b; cols [0,512)=emb[helper[b,t]], [512,1024)=init[b]
// ---------------------------------------------------------------------------
__global__ __launch_bounds__(256) void build_x0(const float* __restrict__ emb,
                                                const int* __restrict__ helper,
                                                const float* __restrict__ init,
                                                float* __restrict__ X0) {
    int idx = blockIdx.x * 256 + threadIdx.x;
    const int total = Tc * Bc * 1024;
    for (int i = idx; i < total; i += gridDim.x * 256) {
        int m = i >> 10;
        int c = i & 1023;
        int t = m >> 4;
        int b = m & 15;
        float v;
        if (c < 512) {
            int w = helper[b * Tc + t];
            v = emb[(size_t)w * Ec + c];
        } else {
            v = init[b * Ec + (c - 512)];
        }
        X0[i] = v;
    }
}

// ---------------------------------------------------------------------------
// h0 one-step GRU with zero initial state. dup=1 -> input row is [init;init]
// ---------------------------------------------------------------------------
__global__ __launch_bounds__(256) void h0_layer(const float* __restrict__ xin,
                                                const float* __restrict__ Wih,
                                                const float* __restrict__ bih,
                                                const float* __restrict__ bhh,
                                                float* __restrict__ h0out, int dup) {
    __shared__ float xs[1024];
    int b = blockIdx.x >> 2;
    int hseg = blockIdx.x & 3;
    int tid = threadIdx.x;
    for (int i = tid; i < 1024; i += 256)
        xs[i] = dup ? xin[b * 512 + (i & 511)] : xin[b * 1024 + i];
    __syncthreads();
    int hidx = hseg * 256 + tid;
    const float* wr = Wih + (size_t)hidx * 1024;
    const float* wz = Wih + (size_t)(Hc + hidx) * 1024;
    const float* wn = Wih + (size_t)(2 * Hc + hidx) * 1024;
    float ar = 0.f, az = 0.f, an = 0.f;
    for (int k = 0; k < 1024; k += 4) {
        float4 x4 = *(const float4*)&xs[k];
        ar += dot4(*(const float4*)&wr[k], x4);
        az += dot4(*(const float4*)&wz[k], x4);
        an += dot4(*(const float4*)&wn[k], x4);
    }
    float r = sigm(ar + bih[hidx] + bhh[hidx]);
    float z = sigm(az + bih[Hc + hidx] + bhh[Hc + hidx]);
    float n = tanhf(an + bih[2 * Hc + hidx] + r * bhh[2 * Hc + hidx]);
    h0out[b * Hc + hidx] = (1.f - z) * n;  // h_old = 0
}

// ---------------------------------------------------------------------------
// Fused two-layer pipelined 65-round GRU scan.
// 256 blocks x 512 threads, 1 block/CU (LDS 48K static + 96K dynamic = 144 KB).
// Block k owns h-indices [4k,4k+4) of BOTH layers. LDS holds 12 rows each of
// W_hh0, W_ih1, W_hh1 for the whole scan. Round t: layer-0 step t (t<64) and
// layer-1 step t-1 (t>=1). Layer-1 input x = layer-0 output at time t-1 =
// ys0 slot t -> the SAME slice layer 0 loads this round (shared broadcast).
// Layer-1 x-projection is computed in-scan (fp32, replaces the xp1 GEMM);
// r/z gates sum x- and h-parts pre-sigmoid, n-gate keeps them separate:
//   n = tanh(xn + bih_n + r*(hn + bhh_n)).
// Thread map, butterfly reduce, tree barrier, and agent-scope L3 h exchange
// are identical to the proven single-layer scan. 64 barrier rounds (vs 127).
// ---------------------------------------------------------------------------
__global__ __launch_bounds__(512) void gru_scan2(
    const float* __restrict__ xp0, const float* __restrict__ Whh0,
    const float* __restrict__ bhh0, const float* __restrict__ Wih1,
    const float* __restrict__ Whh1, const float* __restrict__ bih1,
    const float* __restrict__ bhh1, float* __restrict__ ys0,
    float* __restrict__ ys1, unsigned* __restrict__ bar) {
    extern __shared__ float wdyn[];  // [24][1024]: W_ih1 rows then W_hh1 rows
    __shared__ float wh0[12][1024];  // [hl*3+gate][k]  48 KB
    float* wi1 = wdyn;
    float* wh1 = wdyn + 12 * 1024;
    int tid = threadIdx.x;
    int g0 = blockIdx.x * 4;

    // stage 3x12 weight rows (gate-major: row = gate*H + g0+hl) into LDS
    for (int i = tid; i < 12 * 256; i += 512) {
        int r = i >> 8, c = i & 255;
        int hl = r / 3, gate = r % 3;
        size_t row = (size_t)(gate * Hc + g0 + hl) * Hc;
        ((float4*)wh0[r])[c] = ((const float4*)&Whh0[row])[c];
        ((float4*)&wi1[r * 1024])[c] = ((const float4*)&Wih1[row])[c];
        ((float4*)&wh1[r * 1024])[c] = ((const float4*)&Whh1[row])[c];
    }

    int b = tid >> 5;     // batch 0..15
    int kseg = tid & 31;  // k-segment 0..31

    // reducer-lane persistent state
    float bh0[12], brz1[8], bnx1[4], bnh1[4];
    float hold0[4], hold1[4];
    if (kseg == 0) {
#pragma unroll
        for (int r = 0; r < 12; ++r) {
            int hl = r / 3, gate = r % 3;
            bh0[r] = bhh0[gate * Hc + g0 + hl];
        }
#pragma unroll
        for (int hl = 0; hl < 4; ++hl) {
            brz1[hl * 2 + 0] = bih1[g0 + hl] + bhh1[g0 + hl];
            brz1[hl * 2 + 1] = bih1[Hc + g0 + hl] + bhh1[Hc + g0 + hl];
            bnx1[hl] = bih1[2 * Hc + g0 + hl];
            bnh1[hl] = bhh1[2 * Hc + g0 + hl];
        }
        float4 h4 = *(const float4*)&ys0[b * Hc + g0];  // slot 0 = h0 layer0
        hold0[0] = h4.x; hold0[1] = h4.y; hold0[2] = h4.z; hold0[3] = h4.w;
        float4 h5 = *(const float4*)&ys1[b * Hc + g0];  // slot 0 = h0 layer1
        hold1[0] = h5.x; hold1[1] = h5.y; hold1[2] = h5.z; hold1[3] = h5.w;
    }
    __syncthreads();

    unsigned* leaf = bar + (blockIdx.x & 15) * 32;  // 128 B apart
    unsigned* root = bar + 512;

    for (int t = 0; t <= Tc; ++t) {
        const bool doL0 = (t < Tc);
        const bool doL1 = (t > 0);

        // prefetch xp0 gate values for this (t, b): 3 gates x 4 h-idx
        float xg[3][4];
        if (doL0 && kseg == 0) {
            const float* xrow = xp0 + (size_t)(t * Bc + b) * 3072 + g0;
#pragma unroll
            for (int g = 0; g < 3; ++g) {
                float4 v = *(const float4*)&xrow[g * 1024];
                xg[g][0] = v.x; xg[g][1] = v.y; xg[g][2] = v.z; xg[g][3] = v.w;
            }
        }

        // coherent loads: ys0[t] slice (used by L0 h-MAC AND L1 x-MAC),
        // ys1[t-1] slice (L1 h-MAC). 8B atomics, lane-interleaved stride 256B.
        const unsigned long long* h0src =
            (const unsigned long long*)(ys0 + (size_t)t * (Bc * Hc)) + b * 512 + kseg;
        float2 hv0[16];
#pragma unroll
        for (int q = 0; q < 16; ++q)
            hv0[q] = u2f2(__hip_atomic_load(h0src + q * 32, __ATOMIC_RELAXED,
                                            __HIP_MEMORY_SCOPE_AGENT));
        float2 hv1[16];
        if (doL1) {
            const unsigned long long* h1src =
                (const unsigned long long*)(ys1 + (size_t)(t - 1) * (Bc * Hc)) +
                b * 512 + kseg;
#pragma unroll
            for (int q = 0; q < 16; ++q)
                hv1[q] = u2f2(__hip_atomic_load(h1src + q * 32, __ATOMIC_RELAXED,
                                                __HIP_MEMORY_SCOPE_AGENT));
        }

        // layer-0 recurrent MAC: 12 rows vs hv0
        float acc0[12];
        if (doL0) {
#pragma unroll
            for (int r = 0; r < 12; ++r) {
                const float2* w = (const float2*)&wh0[r][kseg * 2];
                float s = 0.f;
#pragma unroll
                for (int q = 0; q < 16; ++q) {
                    float2 ww = w[q * 32];  // +256B per q
                    s += ww.x * hv0[q].x + ww.y * hv0[q].y;
                }
                acc0[r] = s;
            }
        }

        // layer-1 x-proj (vs hv0) + recurrent (vs hv1):
        // a1[hl*4 + {0:r, 1:z, 2:n_x, 3:n_h}]
        float a1[16];
        if (doL1) {
#pragma unroll
            for (int hl = 0; hl < 4; ++hl) {
#pragma unroll
                for (int gate = 0; gate < 3; ++gate) {
                    int r = hl * 3 + gate;
                    const float2* wx = (const float2*)&wi1[r * 1024 + kseg * 2];
                    const float2* wh = (const float2*)&wh1[r * 1024 + kseg * 2];
                    float sx = 0.f, sh = 0.f;
#pragma unroll
                    for (int q = 0; q < 16; ++q) {
                        float2 wwx = wx[q * 32];
                        sx += wwx.x * hv0[q].x + wwx.y * hv0[q].y;
                        float2 wwh = wh[q * 32];
                        sh += wwh.x * hv1[q].x + wwh.y * hv1[q].y;
                    }
                    if (gate < 2)
                        a1[hl * 4 + gate] = sx + sh;
                    else {
                        a1[hl * 4 + 2] = sx;
                        a1[hl * 4 + 3] = sh;
                    }
                }
            }
        }

        // butterfly reduce over 32 ksegs (stays within 32-lane half-wave)
        if (doL0) {
#pragma unroll
            for (int r = 0; r < 12; ++r) {
                float s = acc0[r];
                s += __shfl_xor(s, 1);
                s += __shfl_xor(s, 2);
                s += __shfl_xor(s, 4);
                s += __shfl_xor(s, 8);
                s += __shfl_xor(s, 16);
                acc0[r] = s;
            }
        }
        if (doL1) {
#pragma unroll
            for (int i = 0; i < 16; ++i) {
                float s = a1[i];
                s += __shfl_xor(s, 1);
                s += __shfl_xor(s, 2);
                s += __shfl_xor(s, 4);
                s += __shfl_xor(s, 8);
                s += __shfl_xor(s, 16);
                a1[i] = s;
            }
        }

        if (kseg == 0) {
            if (doL0) {
                float hnew[4];
#pragma unroll
                for (int hl = 0; hl < 4; ++hl) {
                    float r_ = sigm(xg[0][hl] + acc0[hl * 3 + 0] + bh0[hl * 3 + 0]);
                    float z_ = sigm(xg[1][hl] + acc0[hl * 3 + 1] + bh0[hl * 3 + 1]);
                    float n_ =
                        tanhf(xg[2][hl] + r_ * (acc0[hl * 3 + 2] + bh0[hl * 3 + 2]));
                    hnew[hl] = (1.f - z_) * n_ + z_ * hold0[hl];
                    hold0[hl] = hnew[hl];
                }
                unsigned long long* dst = (unsigned long long*)(ys0 +
                    (size_t)(t + 1) * (Bc * Hc) + b * Hc + g0);
                __hip_atomic_store(dst, f22u(hnew[0], hnew[1]), __ATOMIC_RELAXED,
                                   __HIP_MEMORY_SCOPE_AGENT);
                __hip_atomic_store(dst + 1, f22u(hnew[2], hnew[3]), __ATOMIC_RELAXED,
                                   __HIP_MEMORY_SCOPE_AGENT);
            }
            if (doL1) {
                float hnew[4];
#pragma unroll
                for (int hl = 0; hl < 4; ++hl) {
                    float r_ = sigm(a1[hl * 4 + 0] + brz1[hl * 2 + 0]);
                    float z_ = sigm(a1[hl * 4 + 1] + brz1[hl * 2 + 1]);
                    float n_ = tanhf(a1[hl * 4 + 2] + bnx1[hl] +
                                     r_ * (a1[hl * 4 + 3] + bnh1[hl]));
                    hnew[hl] = (1.f - z_) * n_ + z_ * hold1[hl];
                    hold1[hl] = hnew[hl];
                }
                unsigned long long* dst = (unsigned long long*)(ys1 +
                    (size_t)t * (Bc * Hc) + b * Hc + g0);
                __hip_atomic_store(dst, f22u(hnew[0], hnew[1]), __ATOMIC_RELAXED,
                                   __HIP_MEMORY_SCOPE_AGENT);
                __hip_atomic_store(dst + 1, f22u(hnew[2], hnew[3]), __ATOMIC_RELAXED,
                                   __HIP_MEMORY_SCOPE_AGENT);
            }
        }

        if (t < Tc) {
            __syncthreads();  // drains vmcnt: h stores globally visible
            if (tid == 0) {
                unsigned old = __hip_atomic_fetch_add(leaf, 1u, __ATOMIC_RELAXED,
                                                      __HIP_MEMORY_SCOPE_AGENT);
                if (old == (unsigned)(t * 16 + 15))
                    __hip_atomic_fetch_add(root, 1u, __ATOMIC_RELAXED,
                                           __HIP_MEMORY_SCOPE_AGENT);
                unsigned tgt = (unsigned)((t + 1) * 16);
                while (__hip_atomic_load(root, __ATOMIC_RELAXED,
                                         __HIP_MEMORY_SCOPE_AGENT) < tgt)
                    __builtin_amdgcn_s_sleep(1);
            }
            __syncthreads();
        }
    }
}

// ---------------------------------------------------------------------------
// Split-bf16 MFMA GEMM (fp32-accurate): C = act( A @ B^T + bias ), where
// A = Ah + Al, B = Bh + Bl and C = Ah Bh + Ah Bl + Al Bh (3 phases).
// 128x128 tile, BK=32, 4 waves in 2x2, 16x16x32 bf16 MFMA.
// remap=1: output row m=t*B+b stored at row b*T+t. N edge guarded.
// ---------------------------------------------------------------------------
#define GLD_LDS16(g, l)                                                        \
    __builtin_amdgcn_global_load_lds(                                          \
        (const __attribute__((address_space(1))) unsigned int*)(g),            \
        (__attribute__((address_space(3))) unsigned int*)(l), 16, 0, 0)

__global__ __launch_bounds__(256) void mfma_gemm_split(
    const unsigned short* __restrict__ Ah, const unsigned short* __restrict__ Al,
    const unsigned short* __restrict__ Bh, const unsigned short* __restrict__ Bl,
    const float* __restrict__ bias, float* __restrict__ C, int N, int K, int ldc,
    int act, int remap) {
    __shared__ __align__(16) unsigned short As[128 * 32];  // [m][k] 8 KB
    __shared__ __align__(16) unsigned short Bs[128 * 32];  // [n][k] 8 KB
    int tid = threadIdx.x;
    int m0 = blockIdx.y * 128, n0 = blockIdx.x * 128;
    int wave = tid >> 6, lane = tid & 63;
    int mh = (wave >> 1) * 64, nh = (wave & 1) * 64;
    int rlane = lane & 15, k8 = (lane >> 4) * 8;

    f32x4 zero = {0.f, 0.f, 0.f, 0.f};
    f32x4 acc[4][4];
#pragma unroll
    for (int i = 0; i < 4; ++i)
#pragma unroll
        for (int j = 0; j < 4; ++j) acc[i][j] = zero;

    const unsigned short* Ap[3] = {Ah, Al, Ah};
    const unsigned short* Bp[3] = {Bh, Bh, Bl};

    int c0 = tid, c1 = tid + 256;
    int ar0 = m0 + (c0 >> 2), ak0 = (c0 & 3) * 8;
    int ar1 = m0 + (c1 >> 2), ak1 = (c1 & 3) * 8;
    int br0 = n0 + (c0 >> 2);
    int br1 = n0 + (c1 >> 2);
    if (br0 >= N) br0 = N - 1;
    if (br1 >= N) br1 = N - 1;

    for (int ph = 0; ph < 3; ++ph) {
        const unsigned short* Ab = Ap[ph];
        const unsigned short* Bb = Bp[ph];
        for (int kt = 0; kt < K; kt += 32) {
            GLD_LDS16(&Ab[(size_t)ar0 * K + kt + ak0], &As[c0 * 8]);
            GLD_LDS16(&Ab[(size_t)ar1 * K + kt + ak1], &As[c1 * 8]);
            GLD_LDS16(&Bb[(size_t)br0 * K + kt + ak0], &Bs[c0 * 8]);
            GLD_LDS16(&Bb[(size_t)br1 * K + kt + ak1], &Bs[c1 * 8]);
            __syncthreads();
            bf16x8 a[4], b[4];
#pragma unroll
            for (int f = 0; f < 4; ++f)
                a[f] = *(const bf16x8*)&As[(mh + f * 16 + rlane) * 32 + k8];
#pragma unroll
            for (int f = 0; f < 4; ++f)
                b[f] = *(const bf16x8*)&Bs[(nh + f * 16 + rlane) * 32 + k8];
#pragma unroll
            for (int mf = 0; mf < 4; ++mf)
#pragma unroll
                for (int nf = 0; nf < 4; ++nf)
                    acc[mf][nf] = __builtin_amdgcn_mfma_f32_16x16x32_bf16(
                        a[mf], b[nf], acc[mf][nf], 0, 0, 0);
            __syncthreads();
        }
    }

    int quad = lane >> 4;
#pragma unroll
    for (int nf = 0; nf < 4; ++nf) {
        int n = n0 + nh + nf * 16 + rlane;
        if (n >= N) continue;
        float bv = bias ? bias[n] : 0.f;
#pragma unroll
        for (int mf = 0; mf < 4; ++mf) {
#pragma unroll
            for (int r = 0; r < 4; ++r) {
                int m = m0 + mh + mf * 16 + quad * 4 + r;
                float x = acc[mf][nf][r] + bv;
                if (act) x = tanhf(x);
                int orow = remap ? ((m & 15) * Tc + (m >> 4)) : m;
                C[(size_t)orow * ldc + n] = x;
            }
        }
    }
}

// ---------------------------------------------------------------------------
extern "C" void kernel_launch(void* const* d_in, const int* in_sizes, int n_in,
                              void* d_out, int out_size, void* d_ws, size_t ws_size,
                              hipStream_t stream) {
    const float* init   = (const float*)d_in[0];
    const int*   helper = (const int*)d_in[1];
    const float* emb    = (const float*)d_in[2];
    const float* W_ih0  = (const float*)d_in[3];
    const float* W_hh0  = (const float*)d_in[4];
    const float* b_ih0  = (const float*)d_in[5];
    const float* b_hh0  = (const float*)d_in[6];
    const float* W_ih1  = (const float*)d_in[7];
    const float* W_hh1  = (const float*)d_in[8];
    const float* b_ih1  = (const float*)d_in[9];
    const float* b_hh1  = (const float*)d_in[10];
    const float* Wc_w   = (const float*)d_in[11];
    const float* Wc_b   = (const float*)d_in[12];
    float* out = (float*)d_out;

    const int embN = Vc * Ec;

    char* p = (char*)d_ws;
    auto alloc = [&](size_t bytes) {
        char* r = p;
        p += (bytes + 255) & ~(size_t)255;
        return r;
    };
    float* X0   = (float*)alloc((size_t)1048576 * 4);
    float* xp0  = (float*)alloc((size_t)3145728 * 4);
    float* ys0x = (float*)alloc((size_t)65 * 16384 * 4);
    float* ys1x = (float*)alloc((size_t)65 * 16384 * 4);
    float* fin  = (float*)alloc((size_t)524288 * 4);
    unsigned* bar = (unsigned*)alloc(8192);
    unsigned short* embh = (unsigned short*)alloc((size_t)embN * 2);
    unsigned short* embl = (unsigned short*)alloc((size_t)embN * 2);
    unsigned short* X0h  = (unsigned short*)alloc((size_t)1048576 * 2);
    unsigned short* X0l  = (unsigned short*)alloc((size_t)1048576 * 2);
    unsigned short* Wi0h = (unsigned short*)alloc((size_t)3145728 * 2);
    unsigned short* Wi0l = (unsigned short*)alloc((size_t)3145728 * 2);
    unsigned short* Wch  = (unsigned short*)alloc((size_t)524288 * 2);
    unsigned short* Wcl  = (unsigned short*)alloc((size_t)524288 * 2);
    unsigned short* ys1h = (unsigned short*)alloc((size_t)1048576 * 2);
    unsigned short* ys1l = (unsigned short*)alloc((size_t)1048576 * 2);
    unsigned short* finh = (unsigned short*)alloc((size_t)524288 * 2);
    unsigned short* finl = (unsigned short*)alloc((size_t)524288 * 2);

    hipMemsetAsync(bar, 0, 8192, stream);

    auto split = [&](const float* src, unsigned short* h, unsigned short* l, int n) {
        int n4 = n / 4;
        int grid = (n4 + 255) / 256;
        if (grid > 4096) grid = 4096;
        split_bf16_4<<<grid, 256, 0, stream>>>((const float4*)src, (ushort4*)h,
                                               (ushort4*)l, n4);
    };

    split(emb, embh, embl, embN);
    split(W_ih0, Wi0h, Wi0l, 3145728);
    split(Wc_w, Wch, Wcl, 524288);

    h0_layer<<<64, 256, 0, stream>>>(init, W_ih0, b_ih0, b_hh0, ys0x, 1);
    h0_layer<<<64, 256, 0, stream>>>(ys0x, W_ih1, b_ih1, b_hh1, ys1x, 0);

    build_x0<<<1024, 256, 0, stream>>>(emb, helper, init, X0);
    split(X0, X0h, X0l, 1048576);
    mfma_gemm_split<<<dim3(24, 8), 256, 0, stream>>>(X0h, X0l, Wi0h, Wi0l, b_ih0,
                                                     xp0, 3072, 1024, 3072, 0, 0);

    // fused two-layer scan: replaces {scan0, split(ys0), xp1 GEMM, scan1}
    gru_scan2<<<SCAN_BLOCKS, 512, 24 * 1024 * 4, stream>>>(
        xp0, W_hh0, b_hh0, W_ih1, W_hh1, b_ih1, b_hh1, ys0x, ys1x, bar);

    split(ys1x + 16384, ys1h, ys1l, 1048576);
    mfma_gemm_split<<<dim3(4, 8), 256, 0, stream>>>(ys1h, ys1l, Wch, Wcl, Wc_b,
                                                    fin, 512, 1024, 512, 1, 0);

    split(fin, finh, finl, 524288);
    mfma_gemm_split<<<dim3((Vc + 127) / 128, 8), 256, 0, stream>>>(
        finh, finl, embh, embl, nullptr, out, Vc, 512, Vc, 0, 1);
}

// Round 3
// 2272.720 us; speedup vs baseline: 1.0496x; 1.0496x over previous
//
#include <hip/hip_runtime.h>
#include <math.h>

// Problem constants: B=16, T=64, V=50257, E=512, H=1024, L=2
#define Bc 16
#define Tc 64
#define Vc 50257
#define Ec 512
#define Hc 1024
#define SCAN_BLOCKS 256

typedef __attribute__((ext_vector_type(4))) float f32x4;
typedef __attribute__((ext_vector_type(8))) __bf16 bf16x8;

__device__ __forceinline__ float dot4(float4 a, float4 b) {
    return a.x * b.x + a.y * b.y + a.z * b.z + a.w * b.w;
}
__device__ __forceinline__ float sigm(float x) { return 1.0f / (1.0f + expf(-x)); }

// round-to-nearest-even float -> bf16 bits (finite inputs)
__device__ __forceinline__ unsigned short f2b(float f) {
    unsigned u = __float_as_uint(f);
    unsigned r = u + 0x7fffu + ((u >> 16) & 1u);
    return (unsigned short)(r >> 16);
}
__device__ __forceinline__ float b2f(unsigned short b) {
    return __uint_as_float(((unsigned)b) << 16);
}

// ---------------------------------------------------------------------------
// split fp32 -> (hi, lo) bf16 pair, 4 elements/thread
// ---------------------------------------------------------------------------
__global__ __launch_bounds__(256) void split_bf16_4(const float4* __restrict__ x,
                                                    ushort4* __restrict__ hi,
                                                    ushort4* __restrict__ lo, int n4) {
    int i = blockIdx.x * 256 + threadIdx.x;
    for (; i < n4; i += gridDim.x * 256) {
        float4 v = x[i];
        ushort4 h, l;
        h.x = f2b(v.x); l.x = f2b(v.x - b2f(h.x));
        h.y = f2b(v.y); l.y = f2b(v.y - b2f(h.y));
        h.z = f2b(v.z); l.z = f2b(v.z - b2f(h.z));
        h.w = f2b(v.w); l.w = f2b(v.w - b2f(h.w));
        hi[i] = h;
        lo[i] = l;
    }
}

// ---------------------------------------------------------------------------
// Build X0 (T*B, 2E): row m=t*B+b; cols [0,512)=emb[helper[b,t]], [512,1024)=init[b]
// ---------------------------------------------------------------------------
__global__ __launch_bounds__(256) void build_x0(const float* __restrict__ emb,
                                                const int* __restrict__ helper,
                                                const float* __restrict__ init,
                                                float* __restrict__ X0) {
    int idx = blockIdx.x * 256 + threadIdx.x;
    const int total = Tc * Bc * 1024;
    for (int i = idx; i < total; i += gridDim.x * 256) {
        int m = i >> 10;
        int c = i & 1023;
        int t = m >> 4;
        int b = m & 15;
        float v;
        if (c < 512) {
            int w = helper[b * Tc + t];
            v = emb[(size_t)w * Ec + c];
        } else {
            v = init[b * Ec + (c - 512)];
        }
        X0[i] = v;
    }
}

// ---------------------------------------------------------------------------
// h0 one-step GRU with zero initial state. dup=1 -> input row is [init;init].
// Emits fp32 h0 (for chaining) AND bf16 hi/lo into ys slot 0 (for the scan).
// ---------------------------------------------------------------------------
__global__ __launch_bounds__(256) void h0_layer(const float* __restrict__ xin,
                                                const float* __restrict__ Wih,
                                                const float* __restrict__ bih,
                                                const float* __restrict__ bhh,
                                                float* __restrict__ h0out,
                                                unsigned short* __restrict__ ysh,
                                                unsigned short* __restrict__ ysl,
                                                int dup) {
    __shared__ float xs[1024];
    int b = blockIdx.x >> 2;
    int hseg = blockIdx.x & 3;
    int tid = threadIdx.x;
    for (int i = tid; i < 1024; i += 256)
        xs[i] = dup ? xin[b * 512 + (i & 511)] : xin[b * 1024 + i];
    __syncthreads();
    int hidx = hseg * 256 + tid;
    const float* wr = Wih + (size_t)hidx * 1024;
    const float* wz = Wih + (size_t)(Hc + hidx) * 1024;
    const float* wn = Wih + (size_t)(2 * Hc + hidx) * 1024;
    float ar = 0.f, az = 0.f, an = 0.f;
    for (int k = 0; k < 1024; k += 4) {
        float4 x4 = *(const float4*)&xs[k];
        ar += dot4(*(const float4*)&wr[k], x4);
        az += dot4(*(const float4*)&wz[k], x4);
        an += dot4(*(const float4*)&wn[k], x4);
    }
    float r = sigm(ar + bih[hidx] + bhh[hidx]);
    float z = sigm(az + bih[Hc + hidx] + bhh[Hc + hidx]);
    float n = tanhf(an + bih[2 * Hc + hidx] + r * bhh[2 * Hc + hidx]);
    float h = (1.f - z) * n;  // h_old = 0
    h0out[b * Hc + hidx] = h;
    unsigned short hb = f2b(h);
    ysh[b * 1024 + hidx] = hb;
    ysl[b * 1024 + hidx] = f2b(h - b2f(hb));
}

// ---------------------------------------------------------------------------
// MFMA-based 64-step GRU scan. 256 blocks x 64 threads (ONE wave per block).
// Block k owns h-indices [4k,4k+4) = 12 gate-rows (gr = gate*4+hl, gate-major).
// W_hh rows split fp32->bf16 hi/lo ONCE into XOR-swizzled LDS (64 KB).
// Per round t: the wave loads the full h[t] slice (16 b x 1024 k, bf16 hi/lo,
// agent-scope 8B atomic loads) as MFMA B-frags, reads static A-frags (weights)
// from LDS, and runs a 4-pass split product (hh+hl+lh+ll -> rep error ~2^-17,
// fp32-grade) over 32 k-tiles: 128 x mfma_f32_16x16x32_bf16 into 4 k-split
// accumulators. D[gr][b] lands at lane(col=b=lane&15, row=quad*4+reg); a tiny
// LDS transpose hands all 12 gate values for batch b to lane b, which applies
// the GRU gate math in fp32, keeps h_old in registers, and stores h[t+1] as
// bf16 hi/lo pairs (8B agent atomics). Inter-block sync: the proven 16-leaf
// +root tree barrier via agent-scope relaxed atomics + s_sleep poll (all-lane
// poll; 1-wave block => no __syncthreads needed around it).
// ---------------------------------------------------------------------------
__global__ __launch_bounds__(64, 1) void gru_scan_mfma(
    const float* __restrict__ xp, const float* __restrict__ Whh,
    const float* __restrict__ bhh, unsigned short* __restrict__ ysh,
    unsigned short* __restrict__ ysl, unsigned* __restrict__ bar) {
    extern __shared__ unsigned short Wlo[];   // [16*1024] 32 KB (dynamic)
    __shared__ unsigned short Whi[16][1024];  // 32 KB
    __shared__ float dxc[16][16];             // D transpose scratch
    const int lane = threadIdx.x;
    const int g0 = blockIdx.x * 4;
    const int brow = lane & 15;  // A-row (gr) for LDS reads, B-row (b) for h
    const int kq = lane >> 4;    // k-quadrant within a 32-wide k-tile

    // stage 12 weight rows (gr = gate*4+hl), split to hi/lo, XOR-swizzled so
    // a-frag ds_read_b128 across rows 0-15 is bank-conflict-free (G4 fix:
    // byte ^= (row&7)<<4; row stride 2048B would otherwise be 16-way).
    for (int i = lane; i < 12 * 256; i += 64) {
        int r = i >> 8, c = i & 255;
        size_t wrow = (size_t)((r >> 2) * Hc + g0 + (r & 3)) * Hc;
        float4 w4 = *(const float4*)&Whh[wrow + c * 4];
        ushort4 h4, l4;
        h4.x = f2b(w4.x); l4.x = f2b(w4.x - b2f(h4.x));
        h4.y = f2b(w4.y); l4.y = f2b(w4.y - b2f(h4.y));
        h4.z = f2b(w4.z); l4.z = f2b(w4.z - b2f(h4.z));
        h4.w = f2b(w4.w); l4.w = f2b(w4.w - b2f(h4.w));
        int bo = (c * 8) ^ ((r & 7) << 4);
        *(ushort4*)((char*)&Whi[r][0] + bo) = h4;
        *(ushort4*)((char*)&Wlo[r * 1024] + bo) = l4;
    }
    ushort4 z4 = {0, 0, 0, 0};
    for (int i = lane; i < 4 * 256; i += 64) {  // pad rows 12-15 = 0
        int r = 12 + (i >> 8), c = i & 255;
        ((ushort4*)&Whi[r][0])[c] = z4;
        ((ushort4*)&Wlo[r * 1024])[c] = z4;
    }

    float bh[12];
#pragma unroll
    for (int r = 0; r < 12; ++r) bh[r] = bhh[(r >> 2) * Hc + g0 + (r & 3)];

    // hold init from slot 0 (hi+lo reconstruct), lanes 0-15 use it
    float hold[4];
    {
        const unsigned long long* s0h =
            (const unsigned long long*)ysh + (size_t)brow * 256 + blockIdx.x;
        const unsigned long long* s0l =
            (const unsigned long long*)ysl + (size_t)brow * 256 + blockIdx.x;
        union { unsigned long long u; ushort4 s; } ch, cl;
        ch.u = __hip_atomic_load(s0h, __ATOMIC_RELAXED, __HIP_MEMORY_SCOPE_AGENT);
        cl.u = __hip_atomic_load(s0l, __ATOMIC_RELAXED, __HIP_MEMORY_SCOPE_AGENT);
        hold[0] = b2f(ch.s.x) + b2f(cl.s.x);
        hold[1] = b2f(ch.s.y) + b2f(cl.s.y);
        hold[2] = b2f(ch.s.z) + b2f(cl.s.z);
        hold[3] = b2f(ch.s.w) + b2f(cl.s.w);
    }
    __syncthreads();

    const char* wha = (const char*)&Whi[0][0] + brow * 2048;
    const char* wla = (const char*)Wlo + brow * 2048;
    const int swz = (brow & 7) << 4;

    unsigned* leaf = bar + (blockIdx.x & 15) * 32;  // 128 B apart
    unsigned* root = bar + 512;

    for (int t = 0; t < Tc; ++t) {
        // B-frag h loads: 32 k-tiles x 16B (hi & lo) via 2x8B agent atomics
        const unsigned long long* bsh =
            (const unsigned long long*)ysh + (size_t)(t * 16 + brow) * 256 + kq * 2;
        const unsigned long long* bsl =
            (const unsigned long long*)ysl + (size_t)(t * 16 + brow) * 256 + kq * 2;
        unsigned long long vh[64], vl[64];
#pragma unroll
        for (int kt = 0; kt < 32; ++kt) {
            vh[kt * 2] = __hip_atomic_load(bsh + kt * 8, __ATOMIC_RELAXED,
                                           __HIP_MEMORY_SCOPE_AGENT);
            vh[kt * 2 + 1] = __hip_atomic_load(bsh + kt * 8 + 1, __ATOMIC_RELAXED,
                                               __HIP_MEMORY_SCOPE_AGENT);
            vl[kt * 2] = __hip_atomic_load(bsl + kt * 8, __ATOMIC_RELAXED,
                                           __HIP_MEMORY_SCOPE_AGENT);
            vl[kt * 2 + 1] = __hip_atomic_load(bsl + kt * 8 + 1, __ATOMIC_RELAXED,
                                               __HIP_MEMORY_SCOPE_AGENT);
        }
        // xp gate values for (t, b) — plain loads (xp static since GEMM)
        const float* xrow = xp + (size_t)(t * 16 + brow) * 3072 + g0;
        f32x4 xgr = *(const f32x4*)&xrow[0];
        f32x4 xgz = *(const f32x4*)&xrow[1024];
        f32x4 xgn = *(const f32x4*)&xrow[2048];

        f32x4 zz = {0.f, 0.f, 0.f, 0.f};
        f32x4 acc[4];
        acc[0] = zz; acc[1] = zz; acc[2] = zz; acc[3] = zz;
#pragma unroll
        for (int kt = 0; kt < 32; ++kt) {
            bf16x8 ah = *(const bf16x8*)(wha + ((kt * 64 + kq * 16) ^ swz));
            bf16x8 al = *(const bf16x8*)(wla + ((kt * 64 + kq * 16) ^ swz));
            union { unsigned long long u[2]; bf16x8 v; } ch, cl;
            ch.u[0] = vh[kt * 2]; ch.u[1] = vh[kt * 2 + 1];
            cl.u[0] = vl[kt * 2]; cl.u[1] = vl[kt * 2 + 1];
            acc[kt & 3] = __builtin_amdgcn_mfma_f32_16x16x32_bf16(ah, ch.v,
                                                                  acc[kt & 3], 0, 0, 0);
            acc[kt & 3] = __builtin_amdgcn_mfma_f32_16x16x32_bf16(ah, cl.v,
                                                                  acc[kt & 3], 0, 0, 0);
            acc[kt & 3] = __builtin_amdgcn_mfma_f32_16x16x32_bf16(al, ch.v,
                                                                  acc[kt & 3], 0, 0, 0);
            acc[kt & 3] = __builtin_amdgcn_mfma_f32_16x16x32_bf16(al, cl.v,
                                                                  acc[kt & 3], 0, 0, 0);
        }
        f32x4 d = acc[0] + acc[1] + acc[2] + acc[3];
        // transpose D[gr][b] -> lane b via LDS (quad q holds gr = q*4+reg)
        if (kq < 3) *(f32x4*)&dxc[brow][kq * 4] = d;
        __syncthreads();  // 1-wave: just lgkmcnt drain

        if (lane < 16) {
            f32x4 ghr = *(const f32x4*)&dxc[lane][0];
            f32x4 ghz = *(const f32x4*)&dxc[lane][4];
            f32x4 ghn = *(const f32x4*)&dxc[lane][8];
            union { unsigned long long u; ushort4 s; } ph, pl;
            float hn4[4];
#pragma unroll
            for (int hl = 0; hl < 4; ++hl) {
                float r_ = sigm(xgr[hl] + ghr[hl] + bh[hl]);
                float z_ = sigm(xgz[hl] + ghz[hl] + bh[4 + hl]);
                float n_ = tanhf(xgn[hl] + r_ * (ghn[hl] + bh[8 + hl]));
                float h = (1.f - z_) * n_ + z_ * hold[hl];
                hold[hl] = h;
                hn4[hl] = h;
            }
            ph.s.x = f2b(hn4[0]); pl.s.x = f2b(hn4[0] - b2f(ph.s.x));
            ph.s.y = f2b(hn4[1]); pl.s.y = f2b(hn4[1] - b2f(ph.s.y));
            ph.s.z = f2b(hn4[2]); pl.s.z = f2b(hn4[2] - b2f(ph.s.z));
            ph.s.w = f2b(hn4[3]); pl.s.w = f2b(hn4[3] - b2f(ph.s.w));
            unsigned long long* dh = (unsigned long long*)ysh +
                                     (size_t)((t + 1) * 16 + lane) * 256 + blockIdx.x;
            unsigned long long* dl = (unsigned long long*)ysl +
                                     (size_t)((t + 1) * 16 + lane) * 256 + blockIdx.x;
            __hip_atomic_store(dh, ph.u, __ATOMIC_RELAXED, __HIP_MEMORY_SCOPE_AGENT);
            __hip_atomic_store(dl, pl.u, __ATOMIC_RELAXED, __HIP_MEMORY_SCOPE_AGENT);
        }

        if (t < Tc - 1) {
            asm volatile("s_waitcnt vmcnt(0)" ::: "memory");  // h stores drained
            if (lane == 0) {
                unsigned old = __hip_atomic_fetch_add(leaf, 1u, __ATOMIC_RELAXED,
                                                      __HIP_MEMORY_SCOPE_AGENT);
                if (old == (unsigned)(t * 16 + 15))
                    __hip_atomic_fetch_add(root, 1u, __ATOMIC_RELAXED,
                                           __HIP_MEMORY_SCOPE_AGENT);
            }
            unsigned tgt = (unsigned)((t + 1) * 16);
            while (__hip_atomic_load(root, __ATOMIC_RELAXED,
                                     __HIP_MEMORY_SCOPE_AGENT) < tgt)
                __builtin_amdgcn_s_sleep(1);
            asm volatile("" ::: "memory");
        }
    }
}

// ---------------------------------------------------------------------------
// Split-bf16 MFMA GEMM (fp32-accurate): C = act( A @ B^T + bias ), where
// A = Ah + Al, B = Bh + Bl and C = Ah Bh + Ah Bl + Al Bh (3 phases).
// 128x128 tile, BK=32, 4 waves in 2x2, 16x16x32 bf16 MFMA.
// remap=1: output row m=t*B+b stored at row b*T+t. N edge guarded.
// ---------------------------------------------------------------------------
#define GLD_LDS16(g, l)                                                        \
    __builtin_amdgcn_global_load_lds(                                          \
        (const __attribute__((address_space(1))) unsigned int*)(g),            \
        (__attribute__((address_space(3))) unsigned int*)(l), 16, 0, 0)

__global__ __launch_bounds__(256) void mfma_gemm_split(
    const unsigned short* __restrict__ Ah, const unsigned short* __restrict__ Al,
    const unsigned short* __restrict__ Bh, const unsigned short* __restrict__ Bl,
    const float* __restrict__ bias, float* __restrict__ C, int N, int K, int ldc,
    int act, int remap) {
    __shared__ __align__(16) unsigned short As[128 * 32];  // [m][k] 8 KB
    __shared__ __align__(16) unsigned short Bs[128 * 32];  // [n][k] 8 KB
    int tid = threadIdx.x;
    int m0 = blockIdx.y * 128, n0 = blockIdx.x * 128;
    int wave = tid >> 6, lane = tid & 63;
    int mh = (wave >> 1) * 64, nh = (wave & 1) * 64;
    int rlane = lane & 15, k8 = (lane >> 4) * 8;

    f32x4 zero = {0.f, 0.f, 0.f, 0.f};
    f32x4 acc[4][4];
#pragma unroll
    for (int i = 0; i < 4; ++i)
#pragma unroll
        for (int j = 0; j < 4; ++j) acc[i][j] = zero;

    const unsigned short* Ap[3] = {Ah, Al, Ah};
    const unsigned short* Bp[3] = {Bh, Bh, Bl};

    int c0 = tid, c1 = tid + 256;
    int ar0 = m0 + (c0 >> 2), ak0 = (c0 & 3) * 8;
    int ar1 = m0 + (c1 >> 2), ak1 = (c1 & 3) * 8;
    int br0 = n0 + (c0 >> 2);
    int br1 = n0 + (c1 >> 2);
    if (br0 >= N) br0 = N - 1;
    if (br1 >= N) br1 = N - 1;

    for (int ph = 0; ph < 3; ++ph) {
        const unsigned short* Ab = Ap[ph];
        const unsigned short* Bb = Bp[ph];
        for (int kt = 0; kt < K; kt += 32) {
            GLD_LDS16(&Ab[(size_t)ar0 * K + kt + ak0], &As[c0 * 8]);
            GLD_LDS16(&Ab[(size_t)ar1 * K + kt + ak1], &As[c1 * 8]);
            GLD_LDS16(&Bb[(size_t)br0 * K + kt + ak0], &Bs[c0 * 8]);
            GLD_LDS16(&Bb[(size_t)br1 * K + kt + ak1], &Bs[c1 * 8]);
            __syncthreads();
            bf16x8 a[4], b[4];
#pragma unroll
            for (int f = 0; f < 4; ++f)
                a[f] = *(const bf16x8*)&As[(mh + f * 16 + rlane) * 32 + k8];
#pragma unroll
            for (int f = 0; f < 4; ++f)
                b[f] = *(const bf16x8*)&Bs[(nh + f * 16 + rlane) * 32 + k8];
#pragma unroll
            for (int mf = 0; mf < 4; ++mf)
#pragma unroll
                for (int nf = 0; nf < 4; ++nf)
                    acc[mf][nf] = __builtin_amdgcn_mfma_f32_16x16x32_bf16(
                        a[mf], b[nf], acc[mf][nf], 0, 0, 0);
            __syncthreads();
        }
    }

    int quad = lane >> 4;
#pragma unroll
    for (int nf = 0; nf < 4; ++nf) {
        int n = n0 + nh + nf * 16 + rlane;
        if (n >= N) continue;
        float bv = bias ? bias[n] : 0.f;
#pragma unroll
        for (int mf = 0; mf < 4; ++mf) {
#pragma unroll
            for (int r = 0; r < 4; ++r) {
                int m = m0 + mh + mf * 16 + quad * 4 + r;
                float x = acc[mf][nf][r] + bv;
                if (act) x = tanhf(x);
                int orow = remap ? ((m & 15) * Tc + (m >> 4)) : m;
                C[(size_t)orow * ldc + n] = x;
            }
        }
    }
}

// ---------------------------------------------------------------------------
extern "C" void kernel_launch(void* const* d_in, const int* in_sizes, int n_in,
                              void* d_out, int out_size, void* d_ws, size_t ws_size,
                              hipStream_t stream) {
    const float* init   = (const float*)d_in[0];
    const int*   helper = (const int*)d_in[1];
    const float* emb    = (const float*)d_in[2];
    const float* W_ih0  = (const float*)d_in[3];
    const float* W_hh0  = (const float*)d_in[4];
    const float* b_ih0  = (const float*)d_in[5];
    const float* b_hh0  = (const float*)d_in[6];
    const float* W_ih1  = (const float*)d_in[7];
    const float* W_hh1  = (const float*)d_in[8];
    const float* b_ih1  = (const float*)d_in[9];
    const float* b_hh1  = (const float*)d_in[10];
    const float* Wc_w   = (const float*)d_in[11];
    const float* Wc_b   = (const float*)d_in[12];
    float* out = (float*)d_out;

    const int embN = Vc * Ec;
    const size_t ysN = (size_t)65 * 16 * 1024;  // bf16 elements per ys stream

    char* p = (char*)d_ws;
    auto alloc = [&](size_t bytes) {
        char* r = p;
        p += (bytes + 255) & ~(size_t)255;
        return r;
    };
    float* X0   = (float*)alloc((size_t)1048576 * 4);
    float* xp0  = (float*)alloc((size_t)3145728 * 4);
    float* xp1  = (float*)alloc((size_t)3145728 * 4);
    float* fin  = (float*)alloc((size_t)524288 * 4);
    float* h00  = (float*)alloc((size_t)16384 * 4);
    float* h01  = (float*)alloc((size_t)16384 * 4);
    unsigned* bar = (unsigned*)alloc(8192);
    unsigned short* embh = (unsigned short*)alloc((size_t)embN * 2);
    unsigned short* embl = (unsigned short*)alloc((size_t)embN * 2);
    unsigned short* X0h  = (unsigned short*)alloc((size_t)1048576 * 2);
    unsigned short* X0l  = (unsigned short*)alloc((size_t)1048576 * 2);
    unsigned short* Wi0h = (unsigned short*)alloc((size_t)3145728 * 2);
    unsigned short* Wi0l = (unsigned short*)alloc((size_t)3145728 * 2);
    unsigned short* Wi1h = (unsigned short*)alloc((size_t)3145728 * 2);
    unsigned short* Wi1l = (unsigned short*)alloc((size_t)3145728 * 2);
    unsigned short* Wch  = (unsigned short*)alloc((size_t)524288 * 2);
    unsigned short* Wcl  = (unsigned short*)alloc((size_t)524288 * 2);
    unsigned short* ys0h = (unsigned short*)alloc(ysN * 2);
    unsigned short* ys0l = (unsigned short*)alloc(ysN * 2);
    unsigned short* ys1h = (unsigned short*)alloc(ysN * 2);
    unsigned short* ys1l = (unsigned short*)alloc(ysN * 2);
    unsigned short* finh = (unsigned short*)alloc((size_t)524288 * 2);
    unsigned short* finl = (unsigned short*)alloc((size_t)524288 * 2);

    hipMemsetAsync(bar, 0, 8192, stream);

    auto split = [&](const float* src, unsigned short* h, unsigned short* l, int n) {
        int n4 = n / 4;
        int grid = (n4 + 255) / 256;
        if (grid > 4096) grid = 4096;
        split_bf16_4<<<grid, 256, 0, stream>>>((const float4*)src, (ushort4*)h,
                                               (ushort4*)l, n4);
    };

    split(emb, embh, embl, embN);
    split(W_ih0, Wi0h, Wi0l, 3145728);
    split(W_ih1, Wi1h, Wi1l, 3145728);
    split(Wc_w, Wch, Wcl, 524288);

    // h0 chain: layer0 (fp32 out + ys0 slot 0 hi/lo), layer1 (ys1 slot 0)
    h0_layer<<<64, 256, 0, stream>>>(init, W_ih0, b_ih0, b_hh0, h00, ys0h, ys0l, 1);
    h0_layer<<<64, 256, 0, stream>>>(h00, W_ih1, b_ih1, b_hh1, h01, ys1h, ys1l, 0);

    build_x0<<<1024, 256, 0, stream>>>(emb, helper, init, X0);
    split(X0, X0h, X0l, 1048576);
    mfma_gemm_split<<<dim3(24, 8), 256, 0, stream>>>(X0h, X0l, Wi0h, Wi0l, b_ih0,
                                                     xp0, 3072, 1024, 3072, 0, 0);

    // layer-0 scan (MFMA recurrent MAC, emits ys0 hi/lo directly)
    gru_scan_mfma<<<SCAN_BLOCKS, 64, 32768, stream>>>(xp0, W_hh0, b_hh0, ys0h, ys0l,
                                                      bar);

    // xp1 GEMM consumes ys0 hi/lo natively (no split kernel needed)
    mfma_gemm_split<<<dim3(24, 8), 256, 0, stream>>>(ys0h + 16384, ys0l + 16384,
                                                     Wi1h, Wi1l, b_ih1, xp1, 3072,
                                                     1024, 3072, 0, 0);

    gru_scan_mfma<<<SCAN_BLOCKS, 64, 32768, stream>>>(xp1, W_hh1, b_hh1, ys1h, ys1l,
                                                      bar + 1024);

    mfma_gemm_split<<<dim3(4, 8), 256, 0, stream>>>(ys1h + 16384, ys1l + 16384,
                                                    Wch, Wcl, Wc_b, fin, 512, 1024,
                                                    512, 1, 0);

    split(fin, finh, finl, 524288);
    mfma_gemm_split<<<dim3((Vc + 127) / 128, 8), 256, 0, stream>>>(
        finh, finl, embh, embl, nullptr, out, Vc, 512, Vc, 0, 1);
}